// Round 6
// baseline (945.211 us; speedup 1.0000x reference)
//
#include <hip/hip_runtime.h>
#include <hip/hip_fp16.h>
#include <math.h>

__device__ __forceinline__ float leaky(float v){ return v > 0.f ? v : 0.2f*v; }

__device__ __forceinline__ float wredsum(float v){
  #pragma unroll
  for (int o=32;o>0;o>>=1) v += __shfl_xor(v,o,64);
  return v;
}

// ---------------- graph CSR build (by dst) ----------------
__global__ void k_zero(int* p, int n){
  int i = blockIdx.x*blockDim.x + threadIdx.x;
  if (i < n) p[i] = 0;
}

__global__ void k_hist(const int* __restrict__ dst, int* __restrict__ deg, int E){
  int i = blockIdx.x*blockDim.x + threadIdx.x;
  if (i < E) atomicAdd(&deg[dst[i]], 1);
}

__global__ __launch_bounds__(1024) void k_scan(const int* __restrict__ deg, int* __restrict__ off,
                                               int* __restrict__ cur, int N){
  __shared__ int part[1024];
  int t = threadIdx.x;
  int chunk = (N + 1023) >> 10;
  int c0 = t * chunk;
  int sum = 0;
  for (int i=0;i<chunk;i++){ int idx=c0+i; if (idx < N) sum += deg[idx]; }
  part[t] = sum;
  __syncthreads();
  for (int o=1;o<1024;o<<=1){
    int v = (t >= o) ? part[t-o] : 0;
    __syncthreads();
    part[t] += v;
    __syncthreads();
  }
  int run = part[t] - sum;   // exclusive prefix of this chunk
  for (int i=0;i<chunk;i++){
    int idx = c0+i;
    if (idx < N){ off[idx] = run; cur[idx] = run; run += deg[idx]; }
  }
  if (t == 1023) off[N] = part[1023];
}

__global__ void k_scatter(const int* __restrict__ src, const int* __restrict__ dst,
                          int* __restrict__ cur, int* __restrict__ srcs, int E){
  int i = blockIdx.x*blockDim.x + threadIdx.x;
  if (i < E){ int p = atomicAdd(&cur[dst[i]], 1); srcs[p] = src[i]; }
}

// ---------------- edge-logit pre-gather (CSR order, streaming-readable) ----------------
__global__ void k_gel1(const int* __restrict__ srcs, const float* __restrict__ el,
                       float* __restrict__ ge16, int E){
  int t = blockIdx.x*blockDim.x + threadIdx.x;
  if (t >= E*16) return;
  int e = t >> 4, h = t & 15;
  int sv = srcs[e];
  ge16[t] = (h < 10) ? el[sv*10 + h] : -INFINITY;
}

__global__ void k_gel2(const int* __restrict__ srcs, const float* __restrict__ el,
                       float* __restrict__ ge2, int E){
  int e = blockIdx.x*blockDim.x + threadIdx.x;
  if (e < E) ge2[e] = el[srcs[e]];
}

// ---------------- GEMM core macro-ish helpers ----------------
// A [M,64] f32 row-major, B [64,Nn] f32 row-major. 64x64 tile, 256 thr, 4x4/thread.
#define GEMM_BODY                                                                  \
  __shared__ __align__(16) float As[64][68];                                       \
  __shared__ __align__(16) float Bs[64][68];                                       \
  const int m0 = blockIdx.x*64, c0 = blockIdx.y*64;                                \
  const int tid = threadIdx.x;                                                     \
  _Pragma("unroll")                                                                \
  for (int q=0;q<4;q++){                                                           \
    int lin = tid + q*256;                                                         \
    int r = lin >> 4, c4 = (lin & 15) << 2;                                        \
    float4 va = make_float4(0.f,0.f,0.f,0.f);                                      \
    if (m0 + r < M) va = *reinterpret_cast<const float4*>(A + (size_t)(m0+r)*64 + c4); \
    *reinterpret_cast<float4*>(&As[r][c4]) = va;                                   \
    float4 vb = *reinterpret_cast<const float4*>(B + (size_t)r*Nn + c0 + c4);      \
    *reinterpret_cast<float4*>(&Bs[r][c4]) = vb;                                   \
  }                                                                                \
  __syncthreads();                                                                 \
  const int tx = tid & 15, ty = tid >> 4;                                          \
  float acc[4][4] = {};                                                            \
  _Pragma("unroll")                                                                \
  for (int k=0;k<64;k+=4){                                                         \
    float av[4][4], bv[4][4];                                                      \
    _Pragma("unroll")                                                              \
    for (int i=0;i<4;i++){                                                         \
      float4 t = *reinterpret_cast<const float4*>(&As[ty*4+i][k]);                 \
      av[i][0]=t.x; av[i][1]=t.y; av[i][2]=t.z; av[i][3]=t.w;                      \
    }                                                                              \
    _Pragma("unroll")                                                              \
    for (int kk=0;kk<4;kk++){                                                      \
      float4 t = *reinterpret_cast<const float4*>(&Bs[k+kk][tx*4]);                \
      bv[kk][0]=t.x; bv[kk][1]=t.y; bv[kk][2]=t.z; bv[kk][3]=t.w;                  \
    }                                                                              \
    _Pragma("unroll")                                                              \
    for (int kk=0;kk<4;kk++)                                                       \
      _Pragma("unroll")                                                            \
      for (int i=0;i<4;i++)                                                        \
        _Pragma("unroll")                                                          \
        for (int j=0;j<4;j++)                                                      \
          acc[i][j] += av[i][kk]*bv[kk][j];                                        \
  }

// layer-1 GEMM: fp16 output + fused attention-coef epilogue (head = blockIdx.y)
__global__ __launch_bounds__(256, 3)
void k_gemm64_l1(const float* __restrict__ A, const float* __restrict__ B,
                 __half* __restrict__ Ch, int M, int Nn,
                 const float* __restrict__ al, const float* __restrict__ ar,
                 float* __restrict__ el, float* __restrict__ er, int H){
  GEMM_BODY
  #pragma unroll
  for (int i=0;i<4;i++){
    int row = m0 + ty*4 + i;
    if (row < M){
      union { __half2 h[2]; uint2 u; } pk;
      pk.h[0] = __floats2half2_rn(acc[i][0], acc[i][1]);
      pk.h[1] = __floats2half2_rn(acc[i][2], acc[i][3]);
      *reinterpret_cast<uint2*>(Ch + (size_t)row*Nn + c0 + tx*4) = pk.u;
    }
  }
  const int h = blockIdx.y;
  float alv[4], arv[4];
  #pragma unroll
  for (int j=0;j<4;j++){ alv[j] = al[c0 + tx*4 + j]; arv[j] = ar[c0 + tx*4 + j]; }
  #pragma unroll
  for (int i=0;i<4;i++){
    float pl = acc[i][0]*alv[0] + acc[i][1]*alv[1] + acc[i][2]*alv[2] + acc[i][3]*alv[3];
    float pr = acc[i][0]*arv[0] + acc[i][1]*arv[1] + acc[i][2]*arv[2] + acc[i][3]*arv[3];
    #pragma unroll
    for (int o=8;o>0;o>>=1){ pl += __shfl_xor(pl,o,16); pr += __shfl_xor(pr,o,16); }
    int row = m0 + ty*4 + i;
    if (tx == 0 && row < M){
      el[(size_t)row*H + h] = pl;
      er[(size_t)row*H + h] = pr;
    }
  }
}

// layer-2 GEMM: fp16 output only
__global__ __launch_bounds__(256, 3)
void k_gemm64_l2(const float* __restrict__ A, const float* __restrict__ B,
                 __half* __restrict__ Ch, int M, int Nn){
  GEMM_BODY
  #pragma unroll
  for (int i=0;i<4;i++){
    int row = m0 + ty*4 + i;
    if (row < M){
      union { __half2 h[2]; uint2 u; } pk;
      pk.h[0] = __floats2half2_rn(acc[i][0], acc[i][1]);
      pk.h[1] = __floats2half2_rn(acc[i][2], acc[i][3]);
      *reinterpret_cast<uint2*>(Ch + (size_t)row*Nn + c0 + tx*4) = pk.u;
    }
  }
}

// layer2 coef from fp16 payload: el[n] = sum_{128} f2h[n,:]*al2 (one wave per node)
__global__ __launch_bounds__(256) void k_coef2(const __half* __restrict__ f2h, const float* __restrict__ al,
                                               const float* __restrict__ ar, float* __restrict__ el,
                                               float* __restrict__ er, int N){
  int n = blockIdx.x*4 + (threadIdx.x>>6);
  int lane = threadIdx.x & 63;
  if (n >= N) return;
  float2 x = __half22float2(*reinterpret_cast<const __half2*>(f2h + (size_t)n*128 + 2*lane));
  float a0 = al[2*lane], a1 = al[2*lane+1];
  float r0 = ar[2*lane], r1 = ar[2*lane+1];
  float pl = wredsum(x.x*a0 + x.y*a1);
  float pr = wredsum(x.x*r0 + x.y*r1);
  if (lane==0){ el[n]=pl; er[n]=pr; }
}

__device__ __forceinline__ void acc8(float* acc, uint4 raw, float w){
  __half2 a = *reinterpret_cast<__half2*>(&raw.x);
  __half2 b = *reinterpret_cast<__half2*>(&raw.y);
  __half2 c = *reinterpret_cast<__half2*>(&raw.z);
  __half2 d = *reinterpret_cast<__half2*>(&raw.w);
  float2 fa = __half22float2(a), fb = __half22float2(b);
  float2 fc = __half22float2(c), fd = __half22float2(d);
  acc[0] += w*fa.x; acc[1] += w*fa.y; acc[2] += w*fb.x; acc[3] += w*fb.y;
  acc[4] += w*fc.x; acc[5] += w*fc.y; acc[6] += w*fd.x; acc[7] += w*fd.y;
}

// ---------------- layer1 edge aggregation (fp16 payload) ----------------
__global__ __launch_bounds__(256) void k_edge1(const __half* __restrict__ f1h,
                                               const float* __restrict__ ge16,
                                               const float* __restrict__ er,
                                               const int* __restrict__ off,
                                               const int* __restrict__ srcs,
                                               const float* __restrict__ b1,
                                               float* __restrict__ hout, int N){
  __shared__ float sh[4*640];
  const int wid  = threadIdx.x >> 6;
  const int lane = threadIdx.x & 63;
  const int n = blockIdx.x*4 + wid;
  if (n >= N) return;
  const int beg = off[n], end = off[n+1];
  const int h16 = lane & 15;
  const float erh = (h16 < 10) ? er[n*10 + h16] : 0.f;
  float mx = -INFINITY;
  for (int i = beg*16 + lane; i < end*16; i += 64) mx = fmaxf(mx, ge16[i]);
  mx = fmaxf(mx, __shfl_xor(mx,16,64));
  mx = fmaxf(mx, __shfl_xor(mx,32,64));
  const float m = (h16 < 10) ? leaky(mx + erh) : 0.f;
  const int hd0 = lane >> 3;        // head for slot0 (0..7)
  const int hd1 = 8 + (lane >> 3);  // head for slot1 (lanes<16 -> 8..9)
  float s_acc = 0.f;
  float acc0[8] = {0,0,0,0,0,0,0,0};
  float acc1[8] = {0,0,0,0,0,0,0,0};
  for (int c0 = beg; c0 < end; c0 += 64){
    const int sv = (c0 + lane < end) ? srcs[c0 + lane] : 0;
    const int cn = min(64, end - c0);
    for (int j = 0; j < cn; j += 4){
      const int nv = min(4, cn - j);
      int gi = (c0 + j)*16 + lane;
      float wv = (gi < end*16) ? ge16[gi] : -INFINITY;
      float w = __expf(leaky(wv + erh) - m);
      s_acc += w;
      uint4 r0[4], r1[4];
      #pragma unroll
      for (int jj=0; jj<4; jj++){
        if (jj < nv){
          int sj = __shfl(sv, j+jj, 64);
          const __half* rp = f1h + (size_t)sj*640;
          r0[jj] = *reinterpret_cast<const uint4*>(rp + 8*lane);
          r1[jj] = (lane < 16) ? *reinterpret_cast<const uint4*>(rp + 512 + 8*lane)
                               : make_uint4(0,0,0,0);
        }
      }
      #pragma unroll
      for (int jj=0; jj<4; jj++){
        if (jj < nv){
          float w0 = __shfl(w, jj*16 + hd0, 64);
          acc8(acc0, r0[jj], w0);
          float w1 = __shfl(w, jj*16 + hd1, 64);
          acc8(acc1, r1[jj], w1);
        }
      }
    }
  }
  float sred = s_acc;
  sred += __shfl_xor(sred,16,64);
  sred += __shfl_xor(sred,32,64);
  const float rs = (h16 < 10 && sred > 0.f) ? 1.f/sred : 0.f;
  const float rs0 = __shfl(rs, hd0, 64);
  const float rs1 = __shfl(rs, hd1, 64);
  float* sw = sh + wid*640;
  {
    float4 ba = *reinterpret_cast<const float4*>(b1 + 8*lane);
    float4 bb = *reinterpret_cast<const float4*>(b1 + 8*lane + 4);
    float4 oa, ob;
    oa.x = fmaxf(acc0[0]*rs0 + ba.x, 0.f);  oa.y = fmaxf(acc0[1]*rs0 + ba.y, 0.f);
    oa.z = fmaxf(acc0[2]*rs0 + ba.z, 0.f);  oa.w = fmaxf(acc0[3]*rs0 + ba.w, 0.f);
    ob.x = fmaxf(acc0[4]*rs0 + bb.x, 0.f);  ob.y = fmaxf(acc0[5]*rs0 + bb.y, 0.f);
    ob.z = fmaxf(acc0[6]*rs0 + bb.z, 0.f);  ob.w = fmaxf(acc0[7]*rs0 + bb.w, 0.f);
    *reinterpret_cast<float4*>(sw + 8*lane)     = oa;
    *reinterpret_cast<float4*>(sw + 8*lane + 4) = ob;
  }
  if (lane < 16){
    float4 ba = *reinterpret_cast<const float4*>(b1 + 512 + 8*lane);
    float4 bb = *reinterpret_cast<const float4*>(b1 + 512 + 8*lane + 4);
    float4 oa, ob;
    oa.x = fmaxf(acc1[0]*rs1 + ba.x, 0.f);  oa.y = fmaxf(acc1[1]*rs1 + ba.y, 0.f);
    oa.z = fmaxf(acc1[2]*rs1 + ba.z, 0.f);  oa.w = fmaxf(acc1[3]*rs1 + ba.w, 0.f);
    ob.x = fmaxf(acc1[4]*rs1 + bb.x, 0.f);  ob.y = fmaxf(acc1[5]*rs1 + bb.y, 0.f);
    ob.z = fmaxf(acc1[6]*rs1 + bb.z, 0.f);  ob.w = fmaxf(acc1[7]*rs1 + bb.w, 0.f);
    *reinterpret_cast<float4*>(sw + 512 + 8*lane)     = oa;
    *reinterpret_cast<float4*>(sw + 512 + 8*lane + 4) = ob;
  }
  asm volatile("s_waitcnt lgkmcnt(0)" ::: "memory");  // same-wave LDS write->read
  float o = 0.f;
  #pragma unroll
  for (int h=0;h<10;h++) o += sw[h*64 + lane];
  hout[(size_t)n*64 + lane] = o;
}

// ---------------- layer2 edge aggregation: one wave per node, H=1, D=128, fp16 payload ----------------
__global__ __launch_bounds__(256) void k_edge2(const __half* __restrict__ f2h,
                                               const float* __restrict__ ge2,
                                               const float* __restrict__ er,
                                               const int* __restrict__ off,
                                               const int* __restrict__ srcs,
                                               const float* __restrict__ b2,
                                               float* __restrict__ h2, int N){
  int n = blockIdx.x*4 + (threadIdx.x>>6);
  int lane = threadIdx.x & 63;
  if (n >= N) return;
  const int beg = off[n], end = off[n+1];
  const float ern = er[n];
  float mx = -INFINITY;
  for (int i=beg+lane; i<end; i+=64) mx = fmaxf(mx, ge2[i]);
  #pragma unroll
  for (int o=32;o>0;o>>=1) mx = fmaxf(mx, __shfl_xor(mx,o,64));
  const float m = leaky(mx + ern);
  float s = 0.f, ax = 0.f, ay = 0.f;
  for (int c0 = beg; c0 < end; c0 += 64){
    const bool vl = (c0 + lane < end);
    const int sv = vl ? srcs[c0 + lane] : 0;
    const float gv = vl ? ge2[c0 + lane] : -INFINITY;
    const float wv = __expf(leaky(gv + ern) - m);
    s += wv;
    const int cn = min(64, end - c0);
    for (int j = 0; j < cn; j += 4){
      const int nv = min(4, cn - j);
      __half2 p[4];
      #pragma unroll
      for (int jj=0; jj<4; jj++){
        if (jj < nv){
          int sj = __shfl(sv, j+jj, 64);
          p[jj] = *(reinterpret_cast<const __half2*>(f2h + (size_t)sj*128) + lane);
        }
      }
      #pragma unroll
      for (int jj=0; jj<4; jj++){
        if (jj < nv){
          float w = __shfl(wv, j+jj, 64);
          float2 v = __half22float2(p[jj]);
          ax += w*v.x;
          ay += w*v.y;
        }
      }
    }
  }
  s = wredsum(s);
  const float rs = (s > 0.f) ? 1.f/s : 0.f;
  float2 bb = *reinterpret_cast<const float2*>(b2 + 2*lane);
  float2 o;
  o.x = fmaxf(ax*rs + bb.x, 0.f);
  o.y = fmaxf(ay*rs + bb.y, 0.f);
  *reinterpret_cast<float2*>(h2 + (size_t)n*128 + 2*lane) = o;
}

// ---------------- per-graph max readout + 2-layer MLP ----------------
__device__ __forceinline__ int lowerb(const int* a, int n, int v){
  int lo=0, hi=n;
  while (lo < hi){ int mid=(lo+hi)>>1; if (a[mid] < v) lo=mid+1; else hi=mid; }
  return lo;
}

__global__ __launch_bounds__(128) void k_readout(const float* __restrict__ h2, const int* __restrict__ gid,
                                                 const float* __restrict__ lw1, const float* __restrict__ lb1,
                                                 const float* __restrict__ lw2, const float* __restrict__ lb2,
                                                 float* __restrict__ out, int N){
  int b = blockIdx.x, t = threadIdx.x;   // t = channel 0..127
  int lo = lowerb(gid, N, b), hi = lowerb(gid, N, b+1);
  float mx = -INFINITY;
  for (int n=lo; n<hi; ++n) mx = fmaxf(mx, h2[(size_t)n*128 + t]);
  if (hi == lo) mx = 0.f;   // empty-graph / isfinite safety
  __shared__ float gs[128];
  __shared__ float ys[128];
  gs[t] = mx;
  __syncthreads();
  float y = lb1[t];
  for (int k=0;k<128;k++) y += gs[k]*lw1[k*128 + t];
  y = fmaxf(y, 0.f);
  ys[t] = y * lw2[t];
  __syncthreads();
  for (int o=64;o>0;o>>=1){
    if (t < o) ys[t] += ys[t+o];
    __syncthreads();
  }
  if (t == 0) out[b] = fmaxf(ys[0] + lb2[0], 0.f);
}

extern "C" void kernel_launch(void* const* d_in, const int* in_sizes, int n_in,
                              void* d_out, int out_size, void* d_ws, size_t ws_size,
                              hipStream_t stream){
  const float* x   = (const float*)d_in[0];
  const int*   src = (const int*)d_in[1];
  const int*   dst = (const int*)d_in[2];
  const int*   gid = (const int*)d_in[3];
  const float* W1  = (const float*)d_in[4];
  const float* al1 = (const float*)d_in[5];
  const float* ar1 = (const float*)d_in[6];
  const float* b1  = (const float*)d_in[7];
  const float* W2  = (const float*)d_in[8];
  const float* al2 = (const float*)d_in[9];
  const float* ar2 = (const float*)d_in[10];
  const float* b2  = (const float*)d_in[11];
  const float* lw1 = (const float*)d_in[12];
  const float* lb1 = (const float*)d_in[13];
  const float* lw2 = (const float*)d_in[14];
  const float* lb2 = (const float*)d_in[15];
  float* out = (float*)d_out;

  const int N = in_sizes[0] / 64;
  const int E = in_sizes[1];
  const int G = out_size;

  char* w = (char*)d_ws;
  size_t p = 0;
  auto alloc = [&](size_t bytes)->char*{ char* r = w + p; p += (bytes + 255) & ~size_t(255); return r; };
  int*    deg  = (int*)alloc((size_t)N*4);
  int*    off  = (int*)alloc((size_t)(N+1)*4);
  int*    cur  = (int*)alloc((size_t)N*4);
  int*    srcs = (int*)alloc((size_t)E*4);
  float*  el1  = (float*)alloc((size_t)N*10*4);
  float*  er1  = (float*)alloc((size_t)N*10*4);
  float*  h1   = (float*)alloc((size_t)N*64*4);
  float*  ge16 = (float*)alloc((size_t)E*16*4);
  __half* f1h  = (__half*)alloc((size_t)N*640*2);
  __half* f2h  = (__half*)alloc((size_t)N*128*2);
  float*  h2   = (float*)alloc((size_t)N*128*4);
  float*  el2 = el1;
  float*  er2 = er1;
  float*  ge2 = ge16;                  // E floats; ge16 dead after edge1

  const int nwB = (N + 3) / 4;   // 4 waves (nodes) per 256-thread block

  k_zero   <<<dim3((N+255)/256), dim3(256), 0, stream>>>(deg, N);
  k_hist   <<<dim3((E+255)/256), dim3(256), 0, stream>>>(dst, deg, E);
  k_scan   <<<dim3(1),           dim3(1024),0, stream>>>(deg, off, cur, N);
  k_scatter<<<dim3((E+255)/256), dim3(256), 0, stream>>>(src, dst, cur, srcs, E);

  // layer 1: GEMM writes fp16 payload + fused attn-coef epilogue (fp32)
  k_gemm64_l1<<<dim3((N+63)/64, 10), dim3(256), 0, stream>>>(x, W1, f1h, N, 640,
                                                             al1, ar1, el1, er1, 10);
  k_gel1   <<<dim3((E*16+255)/256), dim3(256), 0, stream>>>(srcs, el1, ge16, E);
  k_edge1  <<<dim3(nwB), dim3(256), 0, stream>>>(f1h, ge16, er1, off, srcs, b1, h1, N);

  // layer 2: GEMM writes fp16 payload; coefs+gather from fp16
  k_gemm64_l2<<<dim3((N+63)/64, 2), dim3(256), 0, stream>>>(h1, W2, f2h, N, 128);
  k_coef2  <<<dim3(nwB), dim3(256), 0, stream>>>(f2h, al2, ar2, el2, er2, N);
  k_gel2   <<<dim3((E+255)/256), dim3(256), 0, stream>>>(srcs, el2, ge2, E);
  k_edge2  <<<dim3(nwB), dim3(256), 0, stream>>>(f2h, ge2, er2, off, srcs, b2, h2, N);

  k_readout<<<dim3(G), dim3(128), 0, stream>>>(h2, gid, lw1, lb1, lw2, lb2, out, N);
}

// Round 7
// 265.840 us; speedup vs baseline: 3.5556x; 3.5556x over previous
//
#include <hip/hip_runtime.h>
#include <hip/hip_fp16.h>
#include <math.h>

__device__ __forceinline__ float leaky(float v){ return v > 0.f ? v : 0.2f*v; }

__device__ __forceinline__ float wredsum(float v){
  #pragma unroll
  for (int o=32;o>0;o>>=1) v += __shfl_xor(v,o,64);
  return v;
}

// ---------------- graph CSR build (by dst) ----------------
__global__ void k_zero(int* p, int n){
  int i = blockIdx.x*blockDim.x + threadIdx.x;
  if (i < n) p[i] = 0;
}

__global__ void k_hist(const int* __restrict__ dst, int* __restrict__ deg, int E){
  int i = blockIdx.x*blockDim.x + threadIdx.x;
  if (i < E) atomicAdd(&deg[dst[i]], 1);
}

__global__ __launch_bounds__(1024) void k_scan(const int* __restrict__ deg, int* __restrict__ off,
                                               int* __restrict__ cur, int N){
  __shared__ int part[1024];
  int t = threadIdx.x;
  int chunk = (N + 1023) >> 10;
  int c0 = t * chunk;
  int sum = 0;
  for (int i=0;i<chunk;i++){ int idx=c0+i; if (idx < N) sum += deg[idx]; }
  part[t] = sum;
  __syncthreads();
  for (int o=1;o<1024;o<<=1){
    int v = (t >= o) ? part[t-o] : 0;
    __syncthreads();
    part[t] += v;
    __syncthreads();
  }
  int run = part[t] - sum;   // exclusive prefix of this chunk
  for (int i=0;i<chunk;i++){
    int idx = c0+i;
    if (idx < N){ off[idx] = run; cur[idx] = run; run += deg[idx]; }
  }
  if (t == 1023) off[N] = part[1023];
}

__global__ void k_scatter(const int* __restrict__ src, const int* __restrict__ dst,
                          int* __restrict__ cur, int* __restrict__ srcs, int E){
  int i = blockIdx.x*blockDim.x + threadIdx.x;
  if (i < E){ int p = atomicAdd(&cur[dst[i]], 1); srcs[p] = src[i]; }
}

// ---------------- edge-logit pre-gather (CSR order, streaming-readable) ----------------
__global__ void k_gel1(const int* __restrict__ srcs, const float* __restrict__ el,
                       float* __restrict__ ge16, int E){
  int t = blockIdx.x*blockDim.x + threadIdx.x;
  if (t >= E*16) return;
  int e = t >> 4, h = t & 15;
  int sv = srcs[e];
  ge16[t] = (h < 10) ? el[sv*10 + h] : -INFINITY;
}

__global__ void k_gel2(const int* __restrict__ srcs, const float* __restrict__ el,
                       float* __restrict__ ge2, int E){
  int e = blockIdx.x*blockDim.x + threadIdx.x;
  if (e < E) ge2[e] = el[srcs[e]];
}

// ---------------- GEMM core ----------------
// A [M,64] f32 row-major, B [64,Nn] f32 row-major. 64x64 tile, 256 thr, 4x4/thread.
// k-loop: step 4, unroll 2 (bounded hoist window -> no spill at 128-VGPR cap).
#define GEMM_BODY                                                                  \
  __shared__ __align__(16) float As[64][68];                                       \
  __shared__ __align__(16) float Bs[64][68];                                       \
  const int m0 = blockIdx.x*64, c0 = blockIdx.y*64;                                \
  const int tid = threadIdx.x;                                                     \
  _Pragma("unroll")                                                                \
  for (int q=0;q<4;q++){                                                           \
    int lin = tid + q*256;                                                         \
    int r = lin >> 4, c4 = (lin & 15) << 2;                                        \
    float4 va = make_float4(0.f,0.f,0.f,0.f);                                      \
    if (m0 + r < M) va = *reinterpret_cast<const float4*>(A + (size_t)(m0+r)*64 + c4); \
    *reinterpret_cast<float4*>(&As[r][c4]) = va;                                   \
    float4 vb = *reinterpret_cast<const float4*>(B + (size_t)r*Nn + c0 + c4);      \
    *reinterpret_cast<float4*>(&Bs[r][c4]) = vb;                                   \
  }                                                                                \
  __syncthreads();                                                                 \
  const int tx = tid & 15, ty = tid >> 4;                                          \
  float acc[4][4] = {};                                                            \
  _Pragma("unroll 2")                                                              \
  for (int k=0;k<64;k+=4){                                                         \
    float av[4][4], bv[4][4];                                                      \
    _Pragma("unroll")                                                              \
    for (int i=0;i<4;i++){                                                         \
      float4 t = *reinterpret_cast<const float4*>(&As[ty*4+i][k]);                 \
      av[i][0]=t.x; av[i][1]=t.y; av[i][2]=t.z; av[i][3]=t.w;                      \
    }                                                                              \
    _Pragma("unroll")                                                              \
    for (int kk=0;kk<4;kk++){                                                      \
      float4 t = *reinterpret_cast<const float4*>(&Bs[k+kk][tx*4]);                \
      bv[kk][0]=t.x; bv[kk][1]=t.y; bv[kk][2]=t.z; bv[kk][3]=t.w;                  \
    }                                                                              \
    _Pragma("unroll")                                                              \
    for (int kk=0;kk<4;kk++)                                                       \
      _Pragma("unroll")                                                            \
      for (int i=0;i<4;i++)                                                        \
        _Pragma("unroll")                                                          \
        for (int j=0;j<4;j++)                                                      \
          acc[i][j] += av[i][kk]*bv[kk][j];                                        \
  }

// layer-1 GEMM: fp16 output + fused attention-coef epilogue (head = blockIdx.y)
__global__ __launch_bounds__(256, 4)
void k_gemm64_l1(const float* __restrict__ A, const float* __restrict__ B,
                 __half* __restrict__ Ch, int M, int Nn,
                 const float* __restrict__ al, const float* __restrict__ ar,
                 float* __restrict__ el, float* __restrict__ er, int H){
  GEMM_BODY
  #pragma unroll
  for (int i=0;i<4;i++){
    int row = m0 + ty*4 + i;
    if (row < M){
      union { __half2 h[2]; uint2 u; } pk;
      pk.h[0] = __floats2half2_rn(acc[i][0], acc[i][1]);
      pk.h[1] = __floats2half2_rn(acc[i][2], acc[i][3]);
      *reinterpret_cast<uint2*>(Ch + (size_t)row*Nn + c0 + tx*4) = pk.u;
    }
  }
  const int h = blockIdx.y;
  float alv[4], arv[4];
  #pragma unroll
  for (int j=0;j<4;j++){ alv[j] = al[c0 + tx*4 + j]; arv[j] = ar[c0 + tx*4 + j]; }
  #pragma unroll
  for (int i=0;i<4;i++){
    float pl = acc[i][0]*alv[0] + acc[i][1]*alv[1] + acc[i][2]*alv[2] + acc[i][3]*alv[3];
    float pr = acc[i][0]*arv[0] + acc[i][1]*arv[1] + acc[i][2]*arv[2] + acc[i][3]*arv[3];
    #pragma unroll
    for (int o=8;o>0;o>>=1){ pl += __shfl_xor(pl,o,16); pr += __shfl_xor(pr,o,16); }
    int row = m0 + ty*4 + i;
    if (tx == 0 && row < M){
      el[(size_t)row*H + h] = pl;
      er[(size_t)row*H + h] = pr;
    }
  }
}

// layer-2 GEMM: fp16 output only
__global__ __launch_bounds__(256, 4)
void k_gemm64_l2(const float* __restrict__ A, const float* __restrict__ B,
                 __half* __restrict__ Ch, int M, int Nn){
  GEMM_BODY
  #pragma unroll
  for (int i=0;i<4;i++){
    int row = m0 + ty*4 + i;
    if (row < M){
      union { __half2 h[2]; uint2 u; } pk;
      pk.h[0] = __floats2half2_rn(acc[i][0], acc[i][1]);
      pk.h[1] = __floats2half2_rn(acc[i][2], acc[i][3]);
      *reinterpret_cast<uint2*>(Ch + (size_t)row*Nn + c0 + tx*4) = pk.u;
    }
  }
}

// layer2 coef from fp16 payload: el[n] = sum_{128} f2h[n,:]*al2 (one wave per node)
__global__ __launch_bounds__(256) void k_coef2(const __half* __restrict__ f2h, const float* __restrict__ al,
                                               const float* __restrict__ ar, float* __restrict__ el,
                                               float* __restrict__ er, int N){
  int n = blockIdx.x*4 + (threadIdx.x>>6);
  int lane = threadIdx.x & 63;
  if (n >= N) return;
  float2 x = __half22float2(*reinterpret_cast<const __half2*>(f2h + (size_t)n*128 + 2*lane));
  float a0 = al[2*lane], a1 = al[2*lane+1];
  float r0 = ar[2*lane], r1 = ar[2*lane+1];
  float pl = wredsum(x.x*a0 + x.y*a1);
  float pr = wredsum(x.x*r0 + x.y*r1);
  if (lane==0){ el[n]=pl; er[n]=pr; }
}

__device__ __forceinline__ void acc8(float* acc, uint4 raw, float w){
  __half2 a = *reinterpret_cast<__half2*>(&raw.x);
  __half2 b = *reinterpret_cast<__half2*>(&raw.y);
  __half2 c = *reinterpret_cast<__half2*>(&raw.z);
  __half2 d = *reinterpret_cast<__half2*>(&raw.w);
  float2 fa = __half22float2(a), fb = __half22float2(b);
  float2 fc = __half22float2(c), fd = __half22float2(d);
  acc[0] += w*fa.x; acc[1] += w*fa.y; acc[2] += w*fb.x; acc[3] += w*fb.y;
  acc[4] += w*fc.x; acc[5] += w*fc.y; acc[6] += w*fd.x; acc[7] += w*fd.y;
}

// ---------------- layer1 edge aggregation (fp16 payload) ----------------
__global__ __launch_bounds__(256) void k_edge1(const __half* __restrict__ f1h,
                                               const float* __restrict__ ge16,
                                               const float* __restrict__ er,
                                               const int* __restrict__ off,
                                               const int* __restrict__ srcs,
                                               const float* __restrict__ b1,
                                               float* __restrict__ hout, int N){
  __shared__ float sh[4*640];
  const int wid  = threadIdx.x >> 6;
  const int lane = threadIdx.x & 63;
  const int n = blockIdx.x*4 + wid;
  if (n >= N) return;
  const int beg = off[n], end = off[n+1];
  const int h16 = lane & 15;
  const float erh = (h16 < 10) ? er[n*10 + h16] : 0.f;
  float mx = -INFINITY;
  for (int i = beg*16 + lane; i < end*16; i += 64) mx = fmaxf(mx, ge16[i]);
  mx = fmaxf(mx, __shfl_xor(mx,16,64));
  mx = fmaxf(mx, __shfl_xor(mx,32,64));
  const float m = (h16 < 10) ? leaky(mx + erh) : 0.f;
  const int hd0 = lane >> 3;        // head for slot0 (0..7)
  const int hd1 = 8 + (lane >> 3);  // head for slot1 (lanes<16 -> 8..9)
  float s_acc = 0.f;
  float acc0[8] = {0,0,0,0,0,0,0,0};
  float acc1[8] = {0,0,0,0,0,0,0,0};
  for (int c0 = beg; c0 < end; c0 += 64){
    const int sv = (c0 + lane < end) ? srcs[c0 + lane] : 0;
    const int cn = min(64, end - c0);
    for (int j = 0; j < cn; j += 4){
      const int nv = min(4, cn - j);
      int gi = (c0 + j)*16 + lane;
      float wv = (gi < end*16) ? ge16[gi] : -INFINITY;
      float w = __expf(leaky(wv + erh) - m);
      s_acc += w;
      uint4 r0[4], r1[4];
      #pragma unroll
      for (int jj=0; jj<4; jj++){
        if (jj < nv){
          int sj = __shfl(sv, j+jj, 64);
          const __half* rp = f1h + (size_t)sj*640;
          r0[jj] = *reinterpret_cast<const uint4*>(rp + 8*lane);
          r1[jj] = (lane < 16) ? *reinterpret_cast<const uint4*>(rp + 512 + 8*lane)
                               : make_uint4(0,0,0,0);
        }
      }
      #pragma unroll
      for (int jj=0; jj<4; jj++){
        if (jj < nv){
          float w0 = __shfl(w, jj*16 + hd0, 64);
          acc8(acc0, r0[jj], w0);
          float w1 = __shfl(w, jj*16 + hd1, 64);
          acc8(acc1, r1[jj], w1);
        }
      }
    }
  }
  float sred = s_acc;
  sred += __shfl_xor(sred,16,64);
  sred += __shfl_xor(sred,32,64);
  const float rs = (h16 < 10 && sred > 0.f) ? 1.f/sred : 0.f;
  const float rs0 = __shfl(rs, hd0, 64);
  const float rs1 = __shfl(rs, hd1, 64);
  float* sw = sh + wid*640;
  {
    float4 ba = *reinterpret_cast<const float4*>(b1 + 8*lane);
    float4 bb = *reinterpret_cast<const float4*>(b1 + 8*lane + 4);
    float4 oa, ob;
    oa.x = fmaxf(acc0[0]*rs0 + ba.x, 0.f);  oa.y = fmaxf(acc0[1]*rs0 + ba.y, 0.f);
    oa.z = fmaxf(acc0[2]*rs0 + ba.z, 0.f);  oa.w = fmaxf(acc0[3]*rs0 + ba.w, 0.f);
    ob.x = fmaxf(acc0[4]*rs0 + bb.x, 0.f);  ob.y = fmaxf(acc0[5]*rs0 + bb.y, 0.f);
    ob.z = fmaxf(acc0[6]*rs0 + bb.z, 0.f);  ob.w = fmaxf(acc0[7]*rs0 + bb.w, 0.f);
    *reinterpret_cast<float4*>(sw + 8*lane)     = oa;
    *reinterpret_cast<float4*>(sw + 8*lane + 4) = ob;
  }
  if (lane < 16){
    float4 ba = *reinterpret_cast<const float4*>(b1 + 512 + 8*lane);
    float4 bb = *reinterpret_cast<const float4*>(b1 + 512 + 8*lane + 4);
    float4 oa, ob;
    oa.x = fmaxf(acc1[0]*rs1 + ba.x, 0.f);  oa.y = fmaxf(acc1[1]*rs1 + ba.y, 0.f);
    oa.z = fmaxf(acc1[2]*rs1 + ba.z, 0.f);  oa.w = fmaxf(acc1[3]*rs1 + ba.w, 0.f);
    ob.x = fmaxf(acc1[4]*rs1 + bb.x, 0.f);  ob.y = fmaxf(acc1[5]*rs1 + bb.y, 0.f);
    ob.z = fmaxf(acc1[6]*rs1 + bb.z, 0.f);  ob.w = fmaxf(acc1[7]*rs1 + bb.w, 0.f);
    *reinterpret_cast<float4*>(sw + 512 + 8*lane)     = oa;
    *reinterpret_cast<float4*>(sw + 512 + 8*lane + 4) = ob;
  }
  asm volatile("s_waitcnt lgkmcnt(0)" ::: "memory");  // same-wave LDS write->read
  float o = 0.f;
  #pragma unroll
  for (int h=0;h<10;h++) o += sw[h*64 + lane];
  hout[(size_t)n*64 + lane] = o;
}

// ---------------- layer2 edge aggregation: one wave per node, H=1, D=128, fp16 payload ----------------
__global__ __launch_bounds__(256) void k_edge2(const __half* __restrict__ f2h,
                                               const float* __restrict__ ge2,
                                               const float* __restrict__ er,
                                               const int* __restrict__ off,
                                               const int* __restrict__ srcs,
                                               const float* __restrict__ b2,
                                               float* __restrict__ h2, int N){
  int n = blockIdx.x*4 + (threadIdx.x>>6);
  int lane = threadIdx.x & 63;
  if (n >= N) return;
  const int beg = off[n], end = off[n+1];
  const float ern = er[n];
  float mx = -INFINITY;
  for (int i=beg+lane; i<end; i+=64) mx = fmaxf(mx, ge2[i]);
  #pragma unroll
  for (int o=32;o>0;o>>=1) mx = fmaxf(mx, __shfl_xor(mx,o,64));
  const float m = leaky(mx + ern);
  float s = 0.f, ax = 0.f, ay = 0.f;
  for (int c0 = beg; c0 < end; c0 += 64){
    const bool vl = (c0 + lane < end);
    const int sv = vl ? srcs[c0 + lane] : 0;
    const float gv = vl ? ge2[c0 + lane] : -INFINITY;
    const float wv = __expf(leaky(gv + ern) - m);
    s += wv;
    const int cn = min(64, end - c0);
    for (int j = 0; j < cn; j += 4){
      const int nv = min(4, cn - j);
      __half2 p[4];
      #pragma unroll
      for (int jj=0; jj<4; jj++){
        if (jj < nv){
          int sj = __shfl(sv, j+jj, 64);
          p[jj] = *(reinterpret_cast<const __half2*>(f2h + (size_t)sj*128) + lane);
        }
      }
      #pragma unroll
      for (int jj=0; jj<4; jj++){
        if (jj < nv){
          float w = __shfl(wv, j+jj, 64);
          float2 v = __half22float2(p[jj]);
          ax += w*v.x;
          ay += w*v.y;
        }
      }
    }
  }
  s = wredsum(s);
  const float rs = (s > 0.f) ? 1.f/s : 0.f;
  float2 bb = *reinterpret_cast<const float2*>(b2 + 2*lane);
  float2 o;
  o.x = fmaxf(ax*rs + bb.x, 0.f);
  o.y = fmaxf(ay*rs + bb.y, 0.f);
  *reinterpret_cast<float2*>(h2 + (size_t)n*128 + 2*lane) = o;
}

// ---------------- per-graph max readout + 2-layer MLP ----------------
__device__ __forceinline__ int lowerb(const int* a, int n, int v){
  int lo=0, hi=n;
  while (lo < hi){ int mid=(lo+hi)>>1; if (a[mid] < v) lo=mid+1; else hi=mid; }
  return lo;
}

__global__ __launch_bounds__(128) void k_readout(const float* __restrict__ h2, const int* __restrict__ gid,
                                                 const float* __restrict__ lw1, const float* __restrict__ lb1,
                                                 const float* __restrict__ lw2, const float* __restrict__ lb2,
                                                 float* __restrict__ out, int N){
  int b = blockIdx.x, t = threadIdx.x;   // t = channel 0..127
  int lo = lowerb(gid, N, b), hi = lowerb(gid, N, b+1);
  float mx = -INFINITY;
  for (int n=lo; n<hi; ++n) mx = fmaxf(mx, h2[(size_t)n*128 + t]);
  if (hi == lo) mx = 0.f;   // empty-graph / isfinite safety
  __shared__ float gs[128];
  __shared__ float ys[128];
  gs[t] = mx;
  __syncthreads();
  float y = lb1[t];
  for (int k=0;k<128;k++) y += gs[k]*lw1[k*128 + t];
  y = fmaxf(y, 0.f);
  ys[t] = y * lw2[t];
  __syncthreads();
  for (int o=64;o>0;o>>=1){
    if (t < o) ys[t] += ys[t+o];
    __syncthreads();
  }
  if (t == 0) out[b] = fmaxf(ys[0] + lb2[0], 0.f);
}

extern "C" void kernel_launch(void* const* d_in, const int* in_sizes, int n_in,
                              void* d_out, int out_size, void* d_ws, size_t ws_size,
                              hipStream_t stream){
  const float* x   = (const float*)d_in[0];
  const int*   src = (const int*)d_in[1];
  const int*   dst = (const int*)d_in[2];
  const int*   gid = (const int*)d_in[3];
  const float* W1  = (const float*)d_in[4];
  const float* al1 = (const float*)d_in[5];
  const float* ar1 = (const float*)d_in[6];
  const float* b1  = (const float*)d_in[7];
  const float* W2  = (const float*)d_in[8];
  const float* al2 = (const float*)d_in[9];
  const float* ar2 = (const float*)d_in[10];
  const float* b2  = (const float*)d_in[11];
  const float* lw1 = (const float*)d_in[12];
  const float* lb1 = (const float*)d_in[13];
  const float* lw2 = (const float*)d_in[14];
  const float* lb2 = (const float*)d_in[15];
  float* out = (float*)d_out;

  const int N = in_sizes[0] / 64;
  const int E = in_sizes[1];
  const int G = out_size;

  char* w = (char*)d_ws;
  size_t p = 0;
  auto alloc = [&](size_t bytes)->char*{ char* r = w + p; p += (bytes + 255) & ~size_t(255); return r; };
  int*    deg  = (int*)alloc((size_t)N*4);
  int*    off  = (int*)alloc((size_t)(N+1)*4);
  int*    cur  = (int*)alloc((size_t)N*4);
  int*    srcs = (int*)alloc((size_t)E*4);
  float*  el1  = (float*)alloc((size_t)N*10*4);
  float*  er1  = (float*)alloc((size_t)N*10*4);
  float*  h1   = (float*)alloc((size_t)N*64*4);
  float*  ge16 = (float*)alloc((size_t)E*16*4);
  __half* f1h  = (__half*)alloc((size_t)N*640*2);
  __half* f2h  = (__half*)alloc((size_t)N*128*2);
  float*  h2   = (float*)alloc((size_t)N*128*4);
  float*  el2 = el1;
  float*  er2 = er1;
  float*  ge2 = ge16;                  // E floats; ge16 dead after edge1

  const int nwB = (N + 3) / 4;   // 4 waves (nodes) per 256-thread block

  k_zero   <<<dim3((N+255)/256), dim3(256), 0, stream>>>(deg, N);
  k_hist   <<<dim3((E+255)/256), dim3(256), 0, stream>>>(dst, deg, E);
  k_scan   <<<dim3(1),           dim3(1024),0, stream>>>(deg, off, cur, N);
  k_scatter<<<dim3((E+255)/256), dim3(256), 0, stream>>>(src, dst, cur, srcs, E);

  // layer 1: GEMM writes fp16 payload + fused attn-coef epilogue (fp32)
  k_gemm64_l1<<<dim3((N+63)/64, 10), dim3(256), 0, stream>>>(x, W1, f1h, N, 640,
                                                             al1, ar1, el1, er1, 10);
  k_gel1   <<<dim3((E*16+255)/256), dim3(256), 0, stream>>>(srcs, el1, ge16, E);
  k_edge1  <<<dim3(nwB), dim3(256), 0, stream>>>(f1h, ge16, er1, off, srcs, b1, h1, N);

  // layer 2: GEMM writes fp16 payload; coefs+gather from fp16
  k_gemm64_l2<<<dim3((N+63)/64, 2), dim3(256), 0, stream>>>(h1, W2, f2h, N, 128);
  k_coef2  <<<dim3(nwB), dim3(256), 0, stream>>>(f2h, al2, ar2, el2, er2, N);
  k_gel2   <<<dim3((E+255)/256), dim3(256), 0, stream>>>(srcs, el2, ge2, E);
  k_edge2  <<<dim3(nwB), dim3(256), 0, stream>>>(f2h, ge2, er2, off, srcs, b2, h2, N);

  k_readout<<<dim3(G), dim3(128), 0, stream>>>(h2, gid, lw1, lb1, lw2, lb2, out, N);
}

// Round 8
// 254.567 us; speedup vs baseline: 3.7130x; 1.0443x over previous
//
#include <hip/hip_runtime.h>
#include <hip/hip_fp16.h>
#include <math.h>

typedef _Float16 half8 __attribute__((ext_vector_type(8)));
typedef float floatx4 __attribute__((ext_vector_type(4)));

__device__ __forceinline__ float leaky(float v){ return v > 0.f ? v : 0.2f*v; }

__device__ __forceinline__ float wredsum(float v){
  #pragma unroll
  for (int o=32;o>0;o>>=1) v += __shfl_xor(v,o,64);
  return v;
}

// ---------------- graph CSR build (by dst) ----------------
__global__ void k_zero(int* p, int n){
  int i = blockIdx.x*blockDim.x + threadIdx.x;
  if (i < n) p[i] = 0;
}

__global__ void k_hist(const int* __restrict__ dst, int* __restrict__ deg, int E){
  int i = blockIdx.x*blockDim.x + threadIdx.x;
  if (i < E) atomicAdd(&deg[dst[i]], 1);
}

__global__ __launch_bounds__(1024) void k_scan(const int* __restrict__ deg, int* __restrict__ off,
                                               int* __restrict__ cur, int N){
  __shared__ int part[1024];
  int t = threadIdx.x;
  int chunk = (N + 1023) >> 10;
  int c0 = t * chunk;
  int sum = 0;
  for (int i=0;i<chunk;i++){ int idx=c0+i; if (idx < N) sum += deg[idx]; }
  part[t] = sum;
  __syncthreads();
  for (int o=1;o<1024;o<<=1){
    int v = (t >= o) ? part[t-o] : 0;
    __syncthreads();
    part[t] += v;
    __syncthreads();
  }
  int run = part[t] - sum;   // exclusive prefix of this chunk
  for (int i=0;i<chunk;i++){
    int idx = c0+i;
    if (idx < N){ off[idx] = run; cur[idx] = run; run += deg[idx]; }
  }
  if (t == 1023) off[N] = part[1023];
}

__global__ void k_scatter(const int* __restrict__ src, const int* __restrict__ dst,
                          int* __restrict__ cur, int* __restrict__ srcs, int E){
  int i = blockIdx.x*blockDim.x + threadIdx.x;
  if (i < E){ int p = atomicAdd(&cur[dst[i]], 1); srcs[p] = src[i]; }
}

// ---------------- prep: fp16 casts + weight transposes ----------------
// xh[i] = x[i]; w1t[c*64+k] = W1[k*640+c]; w2t[c*64+k] = W2[k*128+c]
__global__ void k_prep(const float* __restrict__ x, const float* __restrict__ W1,
                       const float* __restrict__ W2, __half* __restrict__ xh,
                       __half* __restrict__ w1t, __half* __restrict__ w2t, int nx){
  int i = blockIdx.x*blockDim.x + threadIdx.x;
  if (i < nx){ xh[i] = __float2half(x[i]); return; }
  i -= nx;
  if (i < 640*64){ int c = i >> 6, k = i & 63; w1t[i] = __float2half(W1[k*640 + c]); return; }
  i -= 640*64;
  if (i < 128*64){ int c = i >> 6, k = i & 63; w2t[i] = __float2half(W2[k*128 + c]); return; }
}

// ---------------- edge-logit pre-gather (CSR order) ----------------
__global__ void k_gel1(const int* __restrict__ srcs, const float* __restrict__ el,
                       float* __restrict__ ge16, int E){
  int t = blockIdx.x*blockDim.x + threadIdx.x;
  if (t >= E*16) return;
  int e = t >> 4, h = t & 15;
  int sv = srcs[e];
  ge16[t] = (h < 10) ? el[sv*10 + h] : -INFINITY;
}

__global__ void k_gel2(const int* __restrict__ srcs, const float* __restrict__ el,
                       float* __restrict__ ge2, int E){
  int e = blockIdx.x*blockDim.x + threadIdx.x;
  if (e < E) ge2[e] = el[srcs[e]];
}

// ---------------- MFMA GEMM: [M,64] x [64,Ncols] -> fp16, 16x16x32 f16 ----------------
// Block 256 thr = 4 waves; wave w: rows m0+w*16..+15, cols c0..c0+63 (c0 = blockIdx.y*64).
// A lane map: row = l&15, k = (l>>4)*8 + j ; B lane map: col = l&15, same k.
// D lane map: col = l&15, row = (l>>4)*4 + reg.
__global__ __launch_bounds__(256) void k_mfma_l1(const __half* __restrict__ xh,
                                                 const __half* __restrict__ w1t,
                                                 __half* __restrict__ f1h,
                                                 const float* __restrict__ al,
                                                 const float* __restrict__ ar,
                                                 float* __restrict__ el,
                                                 float* __restrict__ er, int M){
  const int w = threadIdx.x >> 6, l = threadIdx.x & 63;
  const int m0 = blockIdx.x*64 + w*16;
  const int h  = blockIdx.y;
  const int c0 = h*64;
  const int lr = l & 15, lk = l >> 4;
  int arow = m0 + lr; if (arow >= M) arow = M-1;
  const half8 a0 = *reinterpret_cast<const half8*>(xh + (size_t)arow*64 + lk*8);
  const half8 a1 = *reinterpret_cast<const half8*>(xh + (size_t)arow*64 + 32 + lk*8);
  floatx4 acc[4];
  #pragma unroll
  for (int t=0;t<4;t++){
    const __half* bp = w1t + (size_t)(c0 + t*16 + lr)*64 + lk*8;
    half8 b0 = *reinterpret_cast<const half8*>(bp);
    half8 b1 = *reinterpret_cast<const half8*>(bp + 32);
    floatx4 z = {0.f,0.f,0.f,0.f};
    z = __builtin_amdgcn_mfma_f32_16x16x32_f16(a0, b0, z, 0, 0, 0);
    z = __builtin_amdgcn_mfma_f32_16x16x32_f16(a1, b1, z, 0, 0, 0);
    acc[t] = z;
  }
  // store fp16 payload
  #pragma unroll
  for (int t=0;t<4;t++)
    #pragma unroll
    for (int j=0;j<4;j++){
      int r = m0 + lk*4 + j;
      if (r < M) f1h[(size_t)r*640 + c0 + t*16 + lr] = __float2half(acc[t][j]);
    }
  // fused attention coef: el[r,h] = sum_c f[r][c]*al[h*64+c]  (this block's 64 cols = head h)
  float pl[4] = {0,0,0,0}, pr[4] = {0,0,0,0};
  #pragma unroll
  for (int t=0;t<4;t++){
    float av = al[c0 + t*16 + lr];
    float rv = ar[c0 + t*16 + lr];
    #pragma unroll
    for (int j=0;j<4;j++){ pl[j] += acc[t][j]*av; pr[j] += acc[t][j]*rv; }
  }
  #pragma unroll
  for (int o=1;o<16;o<<=1)
    #pragma unroll
    for (int j=0;j<4;j++){ pl[j] += __shfl_xor(pl[j],o,64); pr[j] += __shfl_xor(pr[j],o,64); }
  if (lr == 0){
    #pragma unroll
    for (int j=0;j<4;j++){
      int r = m0 + lk*4 + j;
      if (r < M){ el[(size_t)r*10 + h] = pl[j]; er[(size_t)r*10 + h] = pr[j]; }
    }
  }
}

__global__ __launch_bounds__(256) void k_mfma_l2(const __half* __restrict__ ah,
                                                 const __half* __restrict__ wt,
                                                 __half* __restrict__ ch, int M, int Ncols){
  const int w = threadIdx.x >> 6, l = threadIdx.x & 63;
  const int m0 = blockIdx.x*64 + w*16;
  const int c0 = blockIdx.y*64;
  const int lr = l & 15, lk = l >> 4;
  int arow = m0 + lr; if (arow >= M) arow = M-1;
  const half8 a0 = *reinterpret_cast<const half8*>(ah + (size_t)arow*64 + lk*8);
  const half8 a1 = *reinterpret_cast<const half8*>(ah + (size_t)arow*64 + 32 + lk*8);
  floatx4 acc[4];
  #pragma unroll
  for (int t=0;t<4;t++){
    const __half* bp = wt + (size_t)(c0 + t*16 + lr)*64 + lk*8;
    half8 b0 = *reinterpret_cast<const half8*>(bp);
    half8 b1 = *reinterpret_cast<const half8*>(bp + 32);
    floatx4 z = {0.f,0.f,0.f,0.f};
    z = __builtin_amdgcn_mfma_f32_16x16x32_f16(a0, b0, z, 0, 0, 0);
    z = __builtin_amdgcn_mfma_f32_16x16x32_f16(a1, b1, z, 0, 0, 0);
    acc[t] = z;
  }
  #pragma unroll
  for (int t=0;t<4;t++)
    #pragma unroll
    for (int j=0;j<4;j++){
      int r = m0 + lk*4 + j;
      if (r < M) ch[(size_t)r*Ncols + c0 + t*16 + lr] = __float2half(acc[t][j]);
    }
}

// layer2 coef from fp16 payload (one wave per node)
__global__ __launch_bounds__(256) void k_coef2(const __half* __restrict__ f2h, const float* __restrict__ al,
                                               const float* __restrict__ ar, float* __restrict__ el,
                                               float* __restrict__ er, int N){
  int n = blockIdx.x*4 + (threadIdx.x>>6);
  int lane = threadIdx.x & 63;
  if (n >= N) return;
  float2 x = __half22float2(*reinterpret_cast<const __half2*>(f2h + (size_t)n*128 + 2*lane));
  float a0 = al[2*lane], a1 = al[2*lane+1];
  float r0 = ar[2*lane], r1 = ar[2*lane+1];
  float pl = wredsum(x.x*a0 + x.y*a1);
  float pr = wredsum(x.x*r0 + x.y*r1);
  if (lane==0){ el[n]=pl; er[n]=pr; }
}

__device__ __forceinline__ void acc8(float* acc, uint4 raw, float w){
  __half2 a = *reinterpret_cast<__half2*>(&raw.x);
  __half2 b = *reinterpret_cast<__half2*>(&raw.y);
  __half2 c = *reinterpret_cast<__half2*>(&raw.z);
  __half2 d = *reinterpret_cast<__half2*>(&raw.w);
  float2 fa = __half22float2(a), fb = __half22float2(b);
  float2 fc = __half22float2(c), fd = __half22float2(d);
  acc[0] += w*fa.x; acc[1] += w*fa.y; acc[2] += w*fb.x; acc[3] += w*fb.y;
  acc[4] += w*fc.x; acc[5] += w*fc.y; acc[6] += w*fd.x; acc[7] += w*fd.y;
}

// ---------------- layer1 edge aggregation (fp16 payload), 1 wave per node ----------------
__global__ __launch_bounds__(64) void k_edge1(const __half* __restrict__ f1h,
                                              const float* __restrict__ ge16,
                                              const float* __restrict__ er,
                                              const int* __restrict__ off,
                                              const int* __restrict__ srcs,
                                              const float* __restrict__ b1,
                                              __half* __restrict__ h1h, int N){
  __shared__ float sw[640];
  const int lane = threadIdx.x;
  const int n = blockIdx.x;
  if (n >= N) return;
  const int beg = off[n], end = off[n+1];
  const int h16 = lane & 15;
  const float erh = (h16 < 10) ? er[n*10 + h16] : 0.f;
  float mx = -INFINITY;
  for (int i = beg*16 + lane; i < end*16; i += 64) mx = fmaxf(mx, ge16[i]);
  mx = fmaxf(mx, __shfl_xor(mx,16,64));
  mx = fmaxf(mx, __shfl_xor(mx,32,64));
  const float m = (h16 < 10) ? leaky(mx + erh) : 0.f;
  const int hd0 = lane >> 3;        // head for slot0 (0..7)
  const int hd1 = 8 + (lane >> 3);  // head for slot1 (lanes<16 -> 8..9)
  float s_acc = 0.f;
  float acc0[8] = {0,0,0,0,0,0,0,0};
  float acc1[8] = {0,0,0,0,0,0,0,0};
  for (int c0 = beg; c0 < end; c0 += 64){
    const int sv = (c0 + lane < end) ? srcs[c0 + lane] : 0;
    const int cn = min(64, end - c0);
    for (int j = 0; j < cn; j += 4){
      const int nv = min(4, cn - j);
      int gi = (c0 + j)*16 + lane;
      float wv = (gi < end*16) ? ge16[gi] : -INFINITY;
      float w = __expf(leaky(wv + erh) - m);
      s_acc += w;
      uint4 r0[4], r1[4];
      #pragma unroll
      for (int jj=0; jj<4; jj++){
        if (jj < nv){
          int sj = __shfl(sv, j+jj, 64);
          const __half* rp = f1h + (size_t)sj*640;
          r0[jj] = *reinterpret_cast<const uint4*>(rp + 8*lane);
          r1[jj] = (lane < 16) ? *reinterpret_cast<const uint4*>(rp + 512 + 8*lane)
                               : make_uint4(0,0,0,0);
        }
      }
      #pragma unroll
      for (int jj=0; jj<4; jj++){
        if (jj < nv){
          float w0 = __shfl(w, jj*16 + hd0, 64);
          acc8(acc0, r0[jj], w0);
          float w1 = __shfl(w, jj*16 + hd1, 64);
          acc8(acc1, r1[jj], w1);
        }
      }
    }
  }
  float sred = s_acc;
  sred += __shfl_xor(sred,16,64);
  sred += __shfl_xor(sred,32,64);
  const float rs = (h16 < 10 && sred > 0.f) ? 1.f/sred : 0.f;
  const float rs0 = __shfl(rs, hd0, 64);
  const float rs1 = __shfl(rs, hd1, 64);
  {
    float4 ba = *reinterpret_cast<const float4*>(b1 + 8*lane);
    float4 bb = *reinterpret_cast<const float4*>(b1 + 8*lane + 4);
    float4 oa, ob;
    oa.x = fmaxf(acc0[0]*rs0 + ba.x, 0.f);  oa.y = fmaxf(acc0[1]*rs0 + ba.y, 0.f);
    oa.z = fmaxf(acc0[2]*rs0 + ba.z, 0.f);  oa.w = fmaxf(acc0[3]*rs0 + ba.w, 0.f);
    ob.x = fmaxf(acc0[4]*rs0 + bb.x, 0.f);  ob.y = fmaxf(acc0[5]*rs0 + bb.y, 0.f);
    ob.z = fmaxf(acc0[6]*rs0 + bb.z, 0.f);  ob.w = fmaxf(acc0[7]*rs0 + bb.w, 0.f);
    *reinterpret_cast<float4*>(sw + 8*lane)     = oa;
    *reinterpret_cast<float4*>(sw + 8*lane + 4) = ob;
  }
  if (lane < 16){
    float4 ba = *reinterpret_cast<const float4*>(b1 + 512 + 8*lane);
    float4 bb = *reinterpret_cast<const float4*>(b1 + 512 + 8*lane + 4);
    float4 oa, ob;
    oa.x = fmaxf(acc1[0]*rs1 + ba.x, 0.f);  oa.y = fmaxf(acc1[1]*rs1 + ba.y, 0.f);
    oa.z = fmaxf(acc1[2]*rs1 + ba.z, 0.f);  oa.w = fmaxf(acc1[3]*rs1 + ba.w, 0.f);
    ob.x = fmaxf(acc1[4]*rs1 + bb.x, 0.f);  ob.y = fmaxf(acc1[5]*rs1 + bb.y, 0.f);
    ob.z = fmaxf(acc1[6]*rs1 + bb.z, 0.f);  ob.w = fmaxf(acc1[7]*rs1 + bb.w, 0.f);
    *reinterpret_cast<float4*>(sw + 512 + 8*lane)     = oa;
    *reinterpret_cast<float4*>(sw + 512 + 8*lane + 4) = ob;
  }
  asm volatile("s_waitcnt lgkmcnt(0)" ::: "memory");  // same-wave LDS write->read
  float o = 0.f;
  #pragma unroll
  for (int h=0;h<10;h++) o += sw[h*64 + lane];
  h1h[(size_t)n*64 + lane] = __float2half(o);
}

// ---------------- layer2 edge aggregation, 1 wave per node, fp16 payload ----------------
__global__ __launch_bounds__(64) void k_edge2(const __half* __restrict__ f2h,
                                              const float* __restrict__ ge2,
                                              const float* __restrict__ er,
                                              const int* __restrict__ off,
                                              const int* __restrict__ srcs,
                                              const float* __restrict__ b2,
                                              float* __restrict__ h2, int N){
  const int lane = threadIdx.x;
  const int n = blockIdx.x;
  if (n >= N) return;
  const int beg = off[n], end = off[n+1];
  const float ern = er[n];
  float mx = -INFINITY;
  for (int i=beg+lane; i<end; i+=64) mx = fmaxf(mx, ge2[i]);
  #pragma unroll
  for (int o=32;o>0;o>>=1) mx = fmaxf(mx, __shfl_xor(mx,o,64));
  const float m = leaky(mx + ern);
  float s = 0.f, ax = 0.f, ay = 0.f;
  for (int c0 = beg; c0 < end; c0 += 64){
    const bool vl = (c0 + lane < end);
    const int sv = vl ? srcs[c0 + lane] : 0;
    const float gv = vl ? ge2[c0 + lane] : -INFINITY;
    const float wv = __expf(leaky(gv + ern) - m);
    s += wv;
    const int cn = min(64, end - c0);
    for (int j = 0; j < cn; j += 4){
      const int nv = min(4, cn - j);
      __half2 p[4];
      #pragma unroll
      for (int jj=0; jj<4; jj++){
        if (jj < nv){
          int sj = __shfl(sv, j+jj, 64);
          p[jj] = *(reinterpret_cast<const __half2*>(f2h + (size_t)sj*128) + lane);
        }
      }
      #pragma unroll
      for (int jj=0; jj<4; jj++){
        if (jj < nv){
          float w = __shfl(wv, j+jj, 64);
          float2 v = __half22float2(p[jj]);
          ax += w*v.x;
          ay += w*v.y;
        }
      }
    }
  }
  s = wredsum(s);
  const float rs = (s > 0.f) ? 1.f/s : 0.f;
  float2 bb = *reinterpret_cast<const float2*>(b2 + 2*lane);
  float2 o;
  o.x = fmaxf(ax*rs + bb.x, 0.f);
  o.y = fmaxf(ay*rs + bb.y, 0.f);
  *reinterpret_cast<float2*>(h2 + (size_t)n*128 + 2*lane) = o;
}

// ---------------- per-graph max readout + 2-layer MLP ----------------
__device__ __forceinline__ int lowerb(const int* a, int n, int v){
  int lo=0, hi=n;
  while (lo < hi){ int mid=(lo+hi)>>1; if (a[mid] < v) lo=mid+1; else hi=mid; }
  return lo;
}

__global__ __launch_bounds__(128) void k_readout(const float* __restrict__ h2, const int* __restrict__ gid,
                                                 const float* __restrict__ lw1, const float* __restrict__ lb1,
                                                 const float* __restrict__ lw2, const float* __restrict__ lb2,
                                                 float* __restrict__ out, int N){
  int b = blockIdx.x, t = threadIdx.x;   // t = channel 0..127
  int lo = lowerb(gid, N, b), hi = lowerb(gid, N, b+1);
  float mx = -INFINITY;
  for (int n=lo; n<hi; ++n) mx = fmaxf(mx, h2[(size_t)n*128 + t]);
  if (hi == lo) mx = 0.f;   // empty-graph / isfinite safety
  __shared__ float gs[128];
  __shared__ float ys[128];
  gs[t] = mx;
  __syncthreads();
  float y = lb1[t];
  for (int k=0;k<128;k++) y += gs[k]*lw1[k*128 + t];
  y = fmaxf(y, 0.f);
  ys[t] = y * lw2[t];
  __syncthreads();
  for (int o=64;o>0;o>>=1){
    if (t < o) ys[t] += ys[t+o];
    __syncthreads();
  }
  if (t == 0) out[b] = fmaxf(ys[0] + lb2[0], 0.f);
}

extern "C" void kernel_launch(void* const* d_in, const int* in_sizes, int n_in,
                              void* d_out, int out_size, void* d_ws, size_t ws_size,
                              hipStream_t stream){
  const float* x   = (const float*)d_in[0];
  const int*   src = (const int*)d_in[1];
  const int*   dst = (const int*)d_in[2];
  const int*   gid = (const int*)d_in[3];
  const float* W1  = (const float*)d_in[4];
  const float* al1 = (const float*)d_in[5];
  const float* ar1 = (const float*)d_in[6];
  const float* b1  = (const float*)d_in[7];
  const float* W2  = (const float*)d_in[8];
  const float* al2 = (const float*)d_in[9];
  const float* ar2 = (const float*)d_in[10];
  const float* b2  = (const float*)d_in[11];
  const float* lw1 = (const float*)d_in[12];
  const float* lb1 = (const float*)d_in[13];
  const float* lw2 = (const float*)d_in[14];
  const float* lb2 = (const float*)d_in[15];
  float* out = (float*)d_out;

  const int N = in_sizes[0] / 64;
  const int E = in_sizes[1];
  const int G = out_size;

  char* w = (char*)d_ws;
  size_t p = 0;
  auto alloc = [&](size_t bytes)->char*{ char* r = w + p; p += (bytes + 255) & ~size_t(255); return r; };
  int*    deg  = (int*)alloc((size_t)N*4);
  int*    off  = (int*)alloc((size_t)(N+1)*4);
  int*    cur  = (int*)alloc((size_t)N*4);
  int*    srcs = (int*)alloc((size_t)E*4);
  float*  el1  = (float*)alloc((size_t)N*10*4);
  float*  er1  = (float*)alloc((size_t)N*10*4);
  float*  ge16 = (float*)alloc((size_t)E*16*4);
  __half* xh   = (__half*)alloc((size_t)N*64*2);
  __half* w1t  = (__half*)alloc((size_t)640*64*2);
  __half* w2t  = (__half*)alloc((size_t)128*64*2);
  __half* f1h  = (__half*)alloc((size_t)N*640*2);
  __half* h1h  = (__half*)alloc((size_t)N*64*2);
  __half* f2h  = (__half*)alloc((size_t)N*128*2);
  float*  h2   = (float*)alloc((size_t)N*128*4);
  float*  el2 = el1;
  float*  er2 = er1;
  float*  ge2 = ge16;                  // E floats; ge16 dead after edge1

  const int nwB = (N + 3) / 4;
  const int prep_total = N*64 + 640*64 + 128*64;
  const int gx = (N + 63) / 64;        // MFMA row-tiles

  k_zero   <<<dim3((N+255)/256), dim3(256), 0, stream>>>(deg, N);
  k_hist   <<<dim3((E+255)/256), dim3(256), 0, stream>>>(dst, deg, E);
  k_scan   <<<dim3(1),           dim3(1024),0, stream>>>(deg, off, cur, N);
  k_scatter<<<dim3((E+255)/256), dim3(256), 0, stream>>>(src, dst, cur, srcs, E);
  k_prep   <<<dim3((prep_total+255)/256), dim3(256), 0, stream>>>(x, W1, W2, xh, w1t, w2t, N*64);

  // layer 1: MFMA GEMM (fp16 in/out, fp32 acc) + fused attn-coef epilogue
  k_mfma_l1<<<dim3(gx, 10), dim3(256), 0, stream>>>(xh, w1t, f1h, al1, ar1, el1, er1, N);
  k_gel1   <<<dim3((E*16+255)/256), dim3(256), 0, stream>>>(srcs, el1, ge16, E);
  k_edge1  <<<dim3(N), dim3(64), 0, stream>>>(f1h, ge16, er1, off, srcs, b1, h1h, N);

  // layer 2: MFMA GEMM from fp16 h1
  k_mfma_l2<<<dim3(gx, 2), dim3(256), 0, stream>>>(h1h, w2t, f2h, N, 128);
  k_coef2  <<<dim3(nwB), dim3(256), 0, stream>>>(f2h, al2, ar2, el2, er2, N);
  k_gel2   <<<dim3((E+255)/256), dim3(256), 0, stream>>>(srcs, el2, ge2, E);
  k_edge2  <<<dim3(N), dim3(64), 0, stream>>>(f2h, ge2, er2, off, srcs, b2, h2, N);

  k_readout<<<dim3(G), dim3(128), 0, stream>>>(h2, gid, lw1, lb1, lw2, lb2, out, N);
}